// Round 10
// baseline (71.673 us; speedup 1.0000x reference)
//
#include <hip/hip_runtime.h>
#include <hip/hip_bf16.h>
#include <cstdint>
#include <cstddef>

// Problem constants (B=8, H=12, S=1024, D=64)
#define HH 12
#define BH 96          // B*H
#define SS 1024
#define DD 64
#define KT 64          // keys per KV tile
#define NT (SS / KT)   // 16 tiles
#define QB 64          // q rows per block (16 per wave)
#define NQT (SS / QB)  // 16

typedef __attribute__((ext_vector_type(4))) float f32x4;
typedef __attribute__((ext_vector_type(8))) short bf16x8;
typedef __attribute__((ext_vector_type(4))) int   i32x4;

#define SCL  0.1803368801111204f   // 0.125 * log2(e)  -> exp2 domain
#define NEGL 1442695.0f            // 1e6  * log2(e)
#define THR  8.0f                  // defer-max threshold (log2 domain)

__device__ __forceinline__ unsigned int pk2(float lo, float hi) {
    __hip_bfloat162 h = __float22bfloat162_rn(float2{lo, hi});
    unsigned int u;
    __builtin_memcpy(&u, &h, sizeof(u));   // v_cvt_pk_bf16_f32
    return u;
}

// ---------------------------------------------------------------------------
// Flash attention, f32 in/out, bf16 MFMA, swapped QK^T (q-row lane-local),
// P fully in-register (permlane32_swap + ds_swizzle xor16), mask folded into
// MFMA C-init, raw v_exp_f32, defer-max (THR=8). Block = 4 waves, 64 q rows;
// grid = (bh, qt): same-bh blocks share an XCD (96 % 8 == 0).
// NEW: double-buffered K/V LDS, ONE barrier per tile:
//   barrier; issue loads(t+1); compute(t) on buf[t&1]; write buf[(t+1)&1].
// Top-of-t barrier orders all compute(t-1) (last readers of buf[(t+1)&1])
// before this wave's write; loads issued after the barrier so the compiler's
// vmcnt(0)-before-s_barrier cannot serialize them against compute.
// K/V LDS XOR-swizzled ([r][e ^ ((r&7)<<3)]).
// ---------------------------------------------------------------------------
__global__ __launch_bounds__(256, 4) void attn_kernel(
        const float* __restrict__ Q,
        const float* __restrict__ Kb,
        const float* __restrict__ Vb,
        const int* __restrict__ mask,
        float* __restrict__ Out) {
    __shared__ unsigned short Klds[2][KT * DD];   // 16 KB
    __shared__ unsigned short Vlds[2][DD * KT];   // 16 KB
    __shared__ float Madd[SS];                    // 4 KB (log2-domain mask add)

    const int tid  = threadIdx.x;
    const int w    = tid >> 6;
    const int lane = tid & 63;
    const int g    = lane >> 4;
    const int l15  = lane & 15;
    const int swq  = (l15 & 7) << 3;

    const int bh = blockIdx.x;
    const int qt = blockIdx.y;
    const int b  = bh / HH;

    // ---- mask table (once per block, log2 domain) ----
    {
        i32x4 m4 = *(const i32x4*)(mask + b * SS + tid * 4);
        f32x4 a;
#pragma unroll
        for (int j = 0; j < 4; ++j) a[j] = m4[j] ? 0.0f : -NEGL;
        *(f32x4*)&Madd[tid * 4] = a;
    }

    // ---- Q fragments (B-operand of swapped QK^T), scaled, exp2 domain ----
    bf16x8 qa[2];
    {
        const float* qp = Q + ((size_t)(bh * SS + qt * QB + w * 16 + l15)) * DD + 8 * g;
#pragma unroll
        for (int c = 0; c < 2; ++c) {
            f32x4 lo = *(const f32x4*)(qp + c * 32);
            f32x4 hi = *(const f32x4*)(qp + c * 32 + 4);
            union { bf16x8 v; unsigned int u[4]; } o;
            o.u[0] = pk2(lo[0] * SCL, lo[1] * SCL);
            o.u[1] = pk2(lo[2] * SCL, lo[3] * SCL);
            o.u[2] = pk2(hi[0] * SCL, hi[1] * SCL);
            o.u[3] = pk2(hi[2] * SCL, hi[3] * SCL);
            qa[c] = o.v;
        }
    }

    // ---- staging registers (round-7/8 verified path) ----
    f32x4 kreg[2][2];
    float vreg[2][8];
    auto load_tile_regs = [&](int t) {
#pragma unroll
        for (int i = 0; i < 2; ++i) {
            int c = tid + i * 256;
            {   // K[key][d0..d0+7], coalesced 32B/lane
                int row = c >> 3, d0 = (c & 7) * 8;
                const float* kp = Kb + ((size_t)(bh * SS + t * KT + row)) * DD + d0;
                kreg[i][0] = *(const f32x4*)kp;
                kreg[i][1] = *(const f32x4*)(kp + 4);
            }
            {   // V^T gather: 8 keys at fixed d (d = lane -> coalesced per j)
                int d = c & 63, k0 = (c >> 6) * 8;
                const float* vp = Vb + ((size_t)(bh * SS + t * KT + k0)) * DD + d;
#pragma unroll
                for (int j = 0; j < 8; ++j) vreg[i][j] = vp[(size_t)j * DD];
            }
        }
    };
    auto write_tile_lds = [&](int pb) {
#pragma unroll
        for (int i = 0; i < 2; ++i) {
            int c = tid + i * 256;
            {
                int row = c >> 3, d0 = (c & 7) * 8;
                union { bf16x8 v; unsigned int u[4]; } kv;
                kv.u[0] = pk2(kreg[i][0][0], kreg[i][0][1]);
                kv.u[1] = pk2(kreg[i][0][2], kreg[i][0][3]);
                kv.u[2] = pk2(kreg[i][1][0], kreg[i][1][1]);
                kv.u[3] = pk2(kreg[i][1][2], kreg[i][1][3]);
                *(bf16x8*)&Klds[pb][row * DD + (d0 ^ ((row & 7) << 3))] = kv.v;
            }
            {
                int d = c & 63, k0 = (c >> 6) * 8;
                union { bf16x8 v; unsigned int u[4]; } vv;
                vv.u[0] = pk2(vreg[i][0], vreg[i][1]);
                vv.u[1] = pk2(vreg[i][2], vreg[i][3]);
                vv.u[2] = pk2(vreg[i][4], vreg[i][5]);
                vv.u[3] = pk2(vreg[i][6], vreg[i][7]);
                *(bf16x8*)&Vlds[pb][d * KT + (k0 ^ ((d & 7) << 3))] = vv.v;
            }
        }
    };

    f32x4 Oacc[4];
#pragma unroll
    for (int dt = 0; dt < 4; ++dt) Oacc[dt] = (f32x4){0.f, 0.f, 0.f, 0.f};
    float mrow = -3.0e38f;     // running max for q = l15 (uniform across g)
    float lrow = 0.f;

    load_tile_regs(0);
    write_tile_lds(0);

    for (int t = 0; t < NT; ++t) {
        const int pb = t & 1;
        __syncthreads();                 // buf[pb] visible; buf[pb^1] free
        if (t + 1 < NT) load_tile_regs(t + 1);   // issue AFTER barrier

        // ---- QK^T (swapped): s4[n][r] = S[key=16n+4g+r][q=l15] ----
        // mask folded into the MFMA C-initializer (D = A·B + C)
        f32x4 s4[4];
        __builtin_amdgcn_s_setprio(1);
#pragma unroll
        for (int n = 0; n < 4; ++n) {
            f32x4 acc = *(const f32x4*)&Madd[t * KT + 16 * n + 4 * g];
#pragma unroll
            for (int c = 0; c < 2; ++c) {
                bf16x8 kb = *(const bf16x8*)
                    &Klds[pb][(16 * n + l15) * DD + ((c * 32 + 8 * g) ^ swq)];
                acc = __builtin_amdgcn_mfma_f32_16x16x32_bf16(kb, qa[c], acc, 0, 0, 0);
            }
            s4[n] = acc;
        }
        __builtin_amdgcn_s_setprio(0);

        // ---- softmax for q=l15: 15 in-lane fmax + 2 shuffles ----
        float tmax;
        {
            f32x4 m4 = s4[0];
#pragma unroll
            for (int n = 1; n < 4; ++n)
#pragma unroll
                for (int r = 0; r < 4; ++r) m4[r] = fmaxf(m4[r], s4[n][r]);
            tmax = fmaxf(fmaxf(m4[0], m4[1]), fmaxf(m4[2], m4[3]));
        }
        tmax = fmaxf(tmax, __shfl_xor(tmax, 16));
        tmax = fmaxf(tmax, __shfl_xor(tmax, 32));

        // ---- defer-max (T13): rescale only when max grew past THR ----
        if (!__all(tmax <= mrow + THR)) {
            float mnew = fmaxf(mrow, tmax);
            float corr = __builtin_amdgcn_exp2f(mrow - mnew);
            mrow = mnew;
            lrow *= corr;
            float corrq[4];
#pragma unroll
            for (int r = 0; r < 4; ++r) corrq[r] = __shfl(corr, 4 * g + r);
#pragma unroll
            for (int dt = 0; dt < 4; ++dt)
#pragma unroll
                for (int r = 0; r < 4; ++r) Oacc[dt][r] *= corrq[r];
        }

        float tsum = 0.f;
        unsigned int pks[4][2];          // bf16-packed P, static-indexed only
#pragma unroll
        for (int n = 0; n < 4; ++n) {
            float p0 = __builtin_amdgcn_exp2f(s4[n][0] - mrow);
            float p1 = __builtin_amdgcn_exp2f(s4[n][1] - mrow);
            float p2 = __builtin_amdgcn_exp2f(s4[n][2] - mrow);
            float p3 = __builtin_amdgcn_exp2f(s4[n][3] - mrow);
            tsum += (p0 + p1) + (p2 + p3);
            pks[n][0] = pk2(p0, p1);
            pks[n][1] = pk2(p2, p3);
        }
        tsum += __shfl_xor(tsum, 16);
        tsum += __shfl_xor(tsum, 32);
        lrow += tsum;

        // ---- PV with in-register A-fragment (permlane32_swap + swz16) ----
        __builtin_amdgcn_s_setprio(1);
        const bool odd = (g & 1);
#pragma unroll
        for (int ks = 0; ks < 2; ++ks) {
            auto sw0 = __builtin_amdgcn_permlane32_swap(pks[2 * ks][0], pks[2 * ks + 1][0], false, false);
            auto sw1 = __builtin_amdgcn_permlane32_swap(pks[2 * ks][1], pks[2 * ks + 1][1], false, false);
            unsigned int S0x = sw0[0], S0y = sw0[1];
            unsigned int S1x = sw1[0], S1y = sw1[1];
            unsigned int T0 = (unsigned int)__builtin_amdgcn_ds_swizzle((int)S0y, 0x401F); // lane^16
            unsigned int U0 = (unsigned int)__builtin_amdgcn_ds_swizzle((int)S0x, 0x401F);
            unsigned int T1 = (unsigned int)__builtin_amdgcn_ds_swizzle((int)S1y, 0x401F);
            unsigned int U1 = (unsigned int)__builtin_amdgcn_ds_swizzle((int)S1x, 0x401F);
            union { bf16x8 v; unsigned int u[4]; } pa;
            pa.u[0] = odd ? T0 : S0x;    // P[q=l15][k=8g+0,1] within 32-key block
            pa.u[1] = odd ? T1 : S1x;    // k=8g+2,3
            pa.u[2] = odd ? S0y : U0;    // k=8g+4,5
            pa.u[3] = odd ? S1y : U1;    // k=8g+6,7
#pragma unroll
            for (int dt = 0; dt < 4; ++dt) {
                bf16x8 vb = *(const bf16x8*)
                    &Vlds[pb][(dt * 16 + l15) * KT + ((ks * 32 + 8 * g) ^ swq)];
                Oacc[dt] = __builtin_amdgcn_mfma_f32_16x16x32_bf16(pa.v, vb, Oacc[dt], 0, 0, 0);
            }
        }
        __builtin_amdgcn_s_setprio(0);

        if (t + 1 < NT) write_tile_lds(pb ^ 1);   // vmcnt drains here, not at barrier
    }

    // ---- epilogue: O[q=4g+r][d=16dt+l15] /= l(q) ----
    float inv = 1.0f / lrow;
    float invq[4];
#pragma unroll
    for (int r = 0; r < 4; ++r) invq[r] = __shfl(inv, 4 * g + r);
    const size_t rowbase = (size_t)(bh * SS + qt * QB + w * 16);
#pragma unroll
    for (int dt = 0; dt < 4; ++dt)
#pragma unroll
        for (int r = 0; r < 4; ++r)
            Out[(rowbase + 4 * g + r) * DD + dt * 16 + l15] = Oacc[dt][r] * invq[r];
}

extern "C" void kernel_launch(void* const* d_in, const int* in_sizes, int n_in,
                              void* d_out, int out_size, void* d_ws, size_t ws_size,
                              hipStream_t stream) {
    const float* Q   = (const float*)d_in[0];
    const float* K   = (const float*)d_in[1];
    const float* V   = (const float*)d_in[2];
    const int* mask  = (const int*)d_in[5];
    float* out       = (float*)d_out;

    attn_kernel<<<dim3(BH, NQT), 256, 0, stream>>>(Q, K, V, mask, out);
}

// Round 11
// 58.990 us; speedup vs baseline: 1.2150x; 1.2150x over previous
//
#include <hip/hip_runtime.h>
#include <hip/hip_bf16.h>
#include <cstdint>
#include <cstddef>

// Problem constants (B=8, H=12, S=1024, D=64)
#define HH 12
#define BH 96          // B*H
#define SS 1024
#define DD 64
#define KT 64          // keys per KV tile
#define NT (SS / KT)   // 16 tiles
#define QB 128         // q rows per block (2 h-halves of 64; 32 q rows per wave)
#define NQT (SS / QB)  // 8

typedef __attribute__((ext_vector_type(4))) float f32x4;
typedef __attribute__((ext_vector_type(8))) short bf16x8;
typedef __attribute__((ext_vector_type(4))) int   i32x4;

#define SCL  0.1803368801111204f   // 0.125 * log2(e)  -> exp2 domain
#define NEGL 1442695.0f            // 1e6  * log2(e)
#define THR  8.0f                  // defer-max threshold (log2 domain)

__device__ __forceinline__ unsigned int pk2(float lo, float hi) {
    __hip_bfloat162 h = __float22bfloat162_rn(float2{lo, hi});
    unsigned int u;
    __builtin_memcpy(&u, &h, sizeof(u));   // v_cvt_pk_bf16_f32
    return u;
}

// ---------------------------------------------------------------------------
// Flash attention, f32 in/out, bf16 MFMA, swapped QK^T (q-row lane-local),
// P fully in-register (permlane32_swap + ds_swizzle xor16), mask folded into
// MFMA C-init, raw v_exp_f32, defer-max (THR=8). Block = 4 waves, 128 q rows
// (two 64-row h-halves per wave; both h share each K-fragment LDS read).
// grid = (bh, qt): same-bh blocks share an XCD (96 % 8 == 0).
// Round-9 verified no-spill schedule: barrier; write LDS(t); barrier;
// issue loads(t+1); compute(t). K/V LDS XOR-swizzled ([r][e ^ ((r&7)<<3)]).
// ---------------------------------------------------------------------------
__global__ __launch_bounds__(256, 3) void attn_kernel(
        const float* __restrict__ Q,
        const float* __restrict__ Kb,
        const float* __restrict__ Vb,
        const int* __restrict__ mask,
        float* __restrict__ Out) {
    __shared__ unsigned short Klds[KT * DD];     // 8 KB
    __shared__ unsigned short Vlds[DD * KT];     // 8 KB
    __shared__ float Madd[SS];                   // 4 KB (log2-domain mask add)

    const int tid  = threadIdx.x;
    const int w    = tid >> 6;
    const int lane = tid & 63;
    const int g    = lane >> 4;
    const int l15  = lane & 15;
    const int swq  = (l15 & 7) << 3;

    const int bh = blockIdx.x;
    const int qt = blockIdx.y;
    const int b  = bh / HH;

    // ---- mask table (once per block, log2 domain) ----
    {
        i32x4 m4 = *(const i32x4*)(mask + b * SS + tid * 4);
        f32x4 a;
#pragma unroll
        for (int j = 0; j < 4; ++j) a[j] = m4[j] ? 0.0f : -NEGL;
        *(f32x4*)&Madd[tid * 4] = a;
    }

    // ---- Q fragments (B-operand of swapped QK^T), both halves, scaled ----
    bf16x8 qa[2][2];
#pragma unroll
    for (int h = 0; h < 2; ++h) {
        const float* qp = Q + ((size_t)(bh * SS + qt * QB + h * 64 + w * 16 + l15)) * DD + 8 * g;
#pragma unroll
        for (int c = 0; c < 2; ++c) {
            f32x4 lo = *(const f32x4*)(qp + c * 32);
            f32x4 hi = *(const f32x4*)(qp + c * 32 + 4);
            union { bf16x8 v; unsigned int u[4]; } o;
            o.u[0] = pk2(lo[0] * SCL, lo[1] * SCL);
            o.u[1] = pk2(lo[2] * SCL, lo[3] * SCL);
            o.u[2] = pk2(hi[0] * SCL, hi[1] * SCL);
            o.u[3] = pk2(hi[2] * SCL, hi[3] * SCL);
            qa[h][c] = o.v;
        }
    }

    // ---- staging registers (verified no-spill path) ----
    f32x4 kreg[2][2];
    float vreg[2][8];
    auto load_tile_regs = [&](int t) {
#pragma unroll
        for (int i = 0; i < 2; ++i) {
            int c = tid + i * 256;
            {   // K[key][d0..d0+7], coalesced 32B/lane
                int row = c >> 3, d0 = (c & 7) * 8;
                const float* kp = Kb + ((size_t)(bh * SS + t * KT + row)) * DD + d0;
                kreg[i][0] = *(const f32x4*)kp;
                kreg[i][1] = *(const f32x4*)(kp + 4);
            }
            {   // V^T gather: 8 keys at fixed d (d = lane -> coalesced per j)
                int d = c & 63, k0 = (c >> 6) * 8;
                const float* vp = Vb + ((size_t)(bh * SS + t * KT + k0)) * DD + d;
#pragma unroll
                for (int j = 0; j < 8; ++j) vreg[i][j] = vp[(size_t)j * DD];
            }
        }
    };
    auto write_tile_lds = [&]() {
#pragma unroll
        for (int i = 0; i < 2; ++i) {
            int c = tid + i * 256;
            {
                int row = c >> 3, d0 = (c & 7) * 8;
                union { bf16x8 v; unsigned int u[4]; } kv;
                kv.u[0] = pk2(kreg[i][0][0], kreg[i][0][1]);
                kv.u[1] = pk2(kreg[i][0][2], kreg[i][0][3]);
                kv.u[2] = pk2(kreg[i][1][0], kreg[i][1][1]);
                kv.u[3] = pk2(kreg[i][1][2], kreg[i][1][3]);
                *(bf16x8*)&Klds[row * DD + (d0 ^ ((row & 7) << 3))] = kv.v;
            }
            {
                int d = c & 63, k0 = (c >> 6) * 8;
                union { bf16x8 v; unsigned int u[4]; } vv;
                vv.u[0] = pk2(vreg[i][0], vreg[i][1]);
                vv.u[1] = pk2(vreg[i][2], vreg[i][3]);
                vv.u[2] = pk2(vreg[i][4], vreg[i][5]);
                vv.u[3] = pk2(vreg[i][6], vreg[i][7]);
                *(bf16x8*)&Vlds[d * KT + (k0 ^ ((d & 7) << 3))] = vv.v;
            }
        }
    };

    f32x4 Oacc[2][4];
#pragma unroll
    for (int h = 0; h < 2; ++h)
#pragma unroll
        for (int dt = 0; dt < 4; ++dt) Oacc[h][dt] = (f32x4){0.f, 0.f, 0.f, 0.f};
    float mrow[2] = {-3.0e38f, -3.0e38f};
    float lrow[2] = {0.f, 0.f};

    load_tile_regs(0);

    for (int t = 0; t < NT; ++t) {
        __syncthreads();                 // all waves done reading tile t-1
        write_tile_lds();
        __syncthreads();                 // tile t visible
        if (t + 1 < NT) load_tile_regs(t + 1);   // latency hidden under compute(t)

        // ---- QK^T (swapped), BOTH h interleaved over shared kb reads ----
        // s4[h][n][r] = S[key=16n+4g+r][q=l15 of half h]; mask in C-init.
        f32x4 s4[2][4];
        __builtin_amdgcn_s_setprio(1);
#pragma unroll
        for (int n = 0; n < 4; ++n) {
            f32x4 m4 = *(const f32x4*)&Madd[t * KT + 16 * n + 4 * g];
            bf16x8 kb0 = *(const bf16x8*)
                &Klds[(16 * n + l15) * DD + ((0 * 32 + 8 * g) ^ swq)];
            bf16x8 kb1 = *(const bf16x8*)
                &Klds[(16 * n + l15) * DD + ((1 * 32 + 8 * g) ^ swq)];
#pragma unroll
            for (int h = 0; h < 2; ++h) {
                f32x4 acc = __builtin_amdgcn_mfma_f32_16x16x32_bf16(kb0, qa[h][0], m4, 0, 0, 0);
                s4[h][n]  = __builtin_amdgcn_mfma_f32_16x16x32_bf16(kb1, qa[h][1], acc, 0, 0, 0);
            }
        }
        __builtin_amdgcn_s_setprio(0);

#pragma unroll
        for (int h = 0; h < 2; ++h) {
            // ---- softmax for q=l15: 15 in-lane fmax + 2 shuffles ----
            float tmax;
            {
                f32x4 m4 = s4[h][0];
#pragma unroll
                for (int n = 1; n < 4; ++n)
#pragma unroll
                    for (int r = 0; r < 4; ++r) m4[r] = fmaxf(m4[r], s4[h][n][r]);
                tmax = fmaxf(fmaxf(m4[0], m4[1]), fmaxf(m4[2], m4[3]));
            }
            tmax = fmaxf(tmax, __shfl_xor(tmax, 16));
            tmax = fmaxf(tmax, __shfl_xor(tmax, 32));

            // ---- defer-max (T13): rescale only when max grew past THR ----
            if (!__all(tmax <= mrow[h] + THR)) {
                float mnew = fmaxf(mrow[h], tmax);
                float corr = __builtin_amdgcn_exp2f(mrow[h] - mnew);
                mrow[h] = mnew;
                lrow[h] *= corr;
                float corrq[4];
#pragma unroll
                for (int r = 0; r < 4; ++r) corrq[r] = __shfl(corr, 4 * g + r);
#pragma unroll
                for (int dt = 0; dt < 4; ++dt)
#pragma unroll
                    for (int r = 0; r < 4; ++r) Oacc[h][dt][r] *= corrq[r];
            }

            float tsum = 0.f;
            unsigned int pks[4][2];      // bf16-packed P, static-indexed only
#pragma unroll
            for (int n = 0; n < 4; ++n) {
                float p0 = __builtin_amdgcn_exp2f(s4[h][n][0] - mrow[h]);
                float p1 = __builtin_amdgcn_exp2f(s4[h][n][1] - mrow[h]);
                float p2 = __builtin_amdgcn_exp2f(s4[h][n][2] - mrow[h]);
                float p3 = __builtin_amdgcn_exp2f(s4[h][n][3] - mrow[h]);
                tsum += (p0 + p1) + (p2 + p3);
                pks[n][0] = pk2(p0, p1);
                pks[n][1] = pk2(p2, p3);
            }
            tsum += __shfl_xor(tsum, 16);
            tsum += __shfl_xor(tsum, 32);
            lrow[h] += tsum;

            // ---- PV with in-register A-fragment (permlane32_swap + swz16) ----
            __builtin_amdgcn_s_setprio(1);
            const bool odd = (g & 1);
#pragma unroll
            for (int ks = 0; ks < 2; ++ks) {
                auto sw0 = __builtin_amdgcn_permlane32_swap(pks[2 * ks][0], pks[2 * ks + 1][0], false, false);
                auto sw1 = __builtin_amdgcn_permlane32_swap(pks[2 * ks][1], pks[2 * ks + 1][1], false, false);
                unsigned int S0x = sw0[0], S0y = sw0[1];
                unsigned int S1x = sw1[0], S1y = sw1[1];
                unsigned int T0 = (unsigned int)__builtin_amdgcn_ds_swizzle((int)S0y, 0x401F); // lane^16
                unsigned int U0 = (unsigned int)__builtin_amdgcn_ds_swizzle((int)S0x, 0x401F);
                unsigned int T1 = (unsigned int)__builtin_amdgcn_ds_swizzle((int)S1y, 0x401F);
                unsigned int U1 = (unsigned int)__builtin_amdgcn_ds_swizzle((int)S1x, 0x401F);
                union { bf16x8 v; unsigned int u[4]; } pa;
                pa.u[0] = odd ? T0 : S0x;    // P[q=l15][k=8g+0,1] within 32-key block
                pa.u[1] = odd ? T1 : S1x;    // k=8g+2,3
                pa.u[2] = odd ? S0y : U0;    // k=8g+4,5
                pa.u[3] = odd ? S1y : U1;    // k=8g+6,7
#pragma unroll
                for (int dt = 0; dt < 4; ++dt) {
                    bf16x8 vb = *(const bf16x8*)
                        &Vlds[(dt * 16 + l15) * KT + ((ks * 32 + 8 * g) ^ swq)];
                    Oacc[h][dt] = __builtin_amdgcn_mfma_f32_16x16x32_bf16(pa.v, vb, Oacc[h][dt], 0, 0, 0);
                }
            }
            __builtin_amdgcn_s_setprio(0);
        }
    }

    // ---- epilogue: O[q=4g+r][d=16dt+l15] /= l(q), both halves ----
#pragma unroll
    for (int h = 0; h < 2; ++h) {
        float inv = 1.0f / lrow[h];
        float invq[4];
#pragma unroll
        for (int r = 0; r < 4; ++r) invq[r] = __shfl(inv, 4 * g + r);
        const size_t rowbase = (size_t)(bh * SS + qt * QB + h * 64 + w * 16);
#pragma unroll
        for (int dt = 0; dt < 4; ++dt)
#pragma unroll
            for (int r = 0; r < 4; ++r)
                Out[(rowbase + 4 * g + r) * DD + dt * 16 + l15] = Oacc[h][dt][r] * invq[r];
    }
}

extern "C" void kernel_launch(void* const* d_in, const int* in_sizes, int n_in,
                              void* d_out, int out_size, void* d_ws, size_t ws_size,
                              hipStream_t stream) {
    const float* Q   = (const float*)d_in[0];
    const float* K   = (const float*)d_in[1];
    const float* V   = (const float*)d_in[2];
    const int* mask  = (const int*)d_in[5];
    float* out       = (float*)d_out;

    attn_kernel<<<dim3(BH, NQT), 256, 0, stream>>>(Q, K, V, mask, out);
}

// Round 12
// 57.089 us; speedup vs baseline: 1.2555x; 1.0333x over previous
//
#include <hip/hip_runtime.h>
#include <hip/hip_bf16.h>
#include <cstdint>
#include <cstddef>

// Problem constants (B=8, H=12, S=1024, D=64)
#define HH 12
#define BH 96          // B*H
#define SS 1024
#define DD 64
#define KT 64          // keys per KV tile
#define NT (SS / KT)   // 16 tiles
#define QB 128         // q rows per block (2 h-halves of 64; 32 q rows per wave)
#define NQT (SS / QB)  // 8

typedef __attribute__((ext_vector_type(2))) float f32x2;
typedef __attribute__((ext_vector_type(4))) float f32x4;
typedef __attribute__((ext_vector_type(8))) short bf16x8;
typedef __attribute__((ext_vector_type(4))) int   i32x4;

#define SCL  0.1803368801111204f   // 0.125 * log2(e)  -> exp2 domain
#define NEGL 1442695.0f            // 1e6  * log2(e)
#define THR  8.0f                  // defer-max threshold (log2 domain)

__device__ __forceinline__ unsigned int pk2(float lo, float hi) {
    __hip_bfloat162 h = __float22bfloat162_rn(float2{lo, hi});
    unsigned int u;
    __builtin_memcpy(&u, &h, sizeof(u));   // v_cvt_pk_bf16_f32
    return u;
}

// ---------------------------------------------------------------------------
// Flash attention, f32 in/out, bf16 MFMA, swapped QK^T (q-row lane-local),
// P fully in-register (permlane32_swap + ds_swizzle xor16), mask folded into
// MFMA C-init, raw v_exp_f32, defer-max (THR=8). Block = 4 waves, 128 q rows
// (two 64-row h-halves per wave; K-fragment reads shared across h in QK^T,
// V-fragment reads shared across h in the joint PV loop).
// V staged with f32x2 row-pair loads (8 VMEM/thread/tile, was 16 scalar).
// grid = (bh, qt): same-bh blocks share an XCD (96 % 8 == 0).
// Verified no-spill schedule: barrier; write LDS(t); barrier; issue
// loads(t+1); compute(t). K/V LDS XOR-swizzled ([r][e ^ ((r&7)<<3)]).
// ---------------------------------------------------------------------------
__global__ __launch_bounds__(256, 3) void attn_kernel(
        const float* __restrict__ Q,
        const float* __restrict__ Kb,
        const float* __restrict__ Vb,
        const int* __restrict__ mask,
        float* __restrict__ Out) {
    __shared__ unsigned short Klds[KT * DD];     // 8 KB
    __shared__ unsigned short Vlds[DD * KT];     // 8 KB
    __shared__ float Madd[SS];                   // 4 KB (log2-domain mask add)

    const int tid  = threadIdx.x;
    const int w    = tid >> 6;
    const int lane = tid & 63;
    const int g    = lane >> 4;
    const int l15  = lane & 15;
    const int swq  = (l15 & 7) << 3;

    const int bh = blockIdx.x;
    const int qt = blockIdx.y;
    const int b  = bh / HH;

    // ---- mask table (once per block, log2 domain) ----
    {
        i32x4 m4 = *(const i32x4*)(mask + b * SS + tid * 4);
        f32x4 a;
#pragma unroll
        for (int j = 0; j < 4; ++j) a[j] = m4[j] ? 0.0f : -NEGL;
        *(f32x4*)&Madd[tid * 4] = a;
    }

    // ---- Q fragments (B-operand of swapped QK^T), both halves, scaled ----
    bf16x8 qa[2][2];
#pragma unroll
    for (int h = 0; h < 2; ++h) {
        const float* qp = Q + ((size_t)(bh * SS + qt * QB + h * 64 + w * 16 + l15)) * DD + 8 * g;
#pragma unroll
        for (int c = 0; c < 2; ++c) {
            f32x4 lo = *(const f32x4*)(qp + c * 32);
            f32x4 hi = *(const f32x4*)(qp + c * 32 + 4);
            union { bf16x8 v; unsigned int u[4]; } o;
            o.u[0] = pk2(lo[0] * SCL, lo[1] * SCL);
            o.u[1] = pk2(lo[2] * SCL, lo[3] * SCL);
            o.u[2] = pk2(hi[0] * SCL, hi[1] * SCL);
            o.u[3] = pk2(hi[2] * SCL, hi[3] * SCL);
            qa[h][c] = o.v;
        }
    }

    // ---- staging registers ----
    f32x4 kreg[2][2];
    f32x2 vreg[8];                       // V row-pair: vreg[j] = V[k0+j][d0], V[k0+j][d0+1]
    const int vd0 = (tid & 31) * 2;      // d-pair
    const int vk0 = (tid >> 5) * 8;      // 8-key run
    auto load_tile_regs = [&](int t) {
#pragma unroll
        for (int i = 0; i < 2; ++i) {
            int c = tid + i * 256;       // K[key][d0..d0+7], coalesced 32B/lane
            int row = c >> 3, d0 = (c & 7) * 8;
            const float* kp = Kb + ((size_t)(bh * SS + t * KT + row)) * DD + d0;
            kreg[i][0] = *(const f32x4*)kp;
            kreg[i][1] = *(const f32x4*)(kp + 4);
        }
        {   // V: 8 x f32x2, 32 lanes x 8B = contiguous 256B per half-wave per j
            const float* vp = Vb + ((size_t)(bh * SS + t * KT + vk0)) * DD + vd0;
#pragma unroll
            for (int j = 0; j < 8; ++j) vreg[j] = *(const f32x2*)(vp + (size_t)j * DD);
        }
    };
    auto write_tile_lds = [&]() {
#pragma unroll
        for (int i = 0; i < 2; ++i) {
            int c = tid + i * 256;
            int row = c >> 3, d0 = (c & 7) * 8;
            union { bf16x8 v; unsigned int u[4]; } kv;
            kv.u[0] = pk2(kreg[i][0][0], kreg[i][0][1]);
            kv.u[1] = pk2(kreg[i][0][2], kreg[i][0][3]);
            kv.u[2] = pk2(kreg[i][1][0], kreg[i][1][1]);
            kv.u[3] = pk2(kreg[i][1][2], kreg[i][1][3]);
            *(bf16x8*)&Klds[row * DD + (d0 ^ ((row & 7) << 3))] = kv.v;
        }
        {   // two V rows (d = vd0, vd0+1), keys vk0..vk0+7
            union { bf16x8 v; unsigned int u[4]; } v0, v1;
            v0.u[0] = pk2(vreg[0][0], vreg[1][0]);
            v0.u[1] = pk2(vreg[2][0], vreg[3][0]);
            v0.u[2] = pk2(vreg[4][0], vreg[5][0]);
            v0.u[3] = pk2(vreg[6][0], vreg[7][0]);
            v1.u[0] = pk2(vreg[0][1], vreg[1][1]);
            v1.u[1] = pk2(vreg[2][1], vreg[3][1]);
            v1.u[2] = pk2(vreg[4][1], vreg[5][1]);
            v1.u[3] = pk2(vreg[6][1], vreg[7][1]);
            *(bf16x8*)&Vlds[vd0 * KT + (vk0 ^ ((vd0 & 7) << 3))] = v0.v;
            *(bf16x8*)&Vlds[(vd0 + 1) * KT + (vk0 ^ (((vd0 + 1) & 7) << 3))] = v1.v;
        }
    };

    f32x4 Oacc0[4], Oacc1[4];
#pragma unroll
    for (int dt = 0; dt < 4; ++dt) {
        Oacc0[dt] = (f32x4){0.f, 0.f, 0.f, 0.f};
        Oacc1[dt] = (f32x4){0.f, 0.f, 0.f, 0.f};
    }
    float m0 = -3.0e38f, m1 = -3.0e38f, l0 = 0.f, l1 = 0.f;

    load_tile_regs(0);

// softmax for one h-half: s -> pk (bf16-packed P), updates mr/lr/Oa.
#define SOFTMAX_H(s, mr, lr, Oa, pk)                                          \
    do {                                                                      \
        float tmax;                                                           \
        {                                                                     \
            f32x4 mm = s[0];                                                  \
            _Pragma("unroll")                                                 \
            for (int n = 1; n < 4; ++n)                                       \
                _Pragma("unroll")                                             \
                for (int r = 0; r < 4; ++r) mm[r] = fmaxf(mm[r], s[n][r]);    \
            tmax = fmaxf(fmaxf(mm[0], mm[1]), fmaxf(mm[2], mm[3]));           \
        }                                                                     \
        tmax = fmaxf(tmax, __shfl_xor(tmax, 16));                             \
        tmax = fmaxf(tmax, __shfl_xor(tmax, 32));                             \
        if (!__all(tmax <= mr + THR)) {                                       \
            float mnew = fmaxf(mr, tmax);                                     \
            float corr = __builtin_amdgcn_exp2f(mr - mnew);                   \
            mr = mnew;                                                        \
            lr *= corr;                                                       \
            float cq[4];                                                      \
            _Pragma("unroll")                                                 \
            for (int r = 0; r < 4; ++r) cq[r] = __shfl(corr, 4 * g + r);      \
            _Pragma("unroll")                                                 \
            for (int dt = 0; dt < 4; ++dt)                                    \
                _Pragma("unroll")                                             \
                for (int r = 0; r < 4; ++r) Oa[dt][r] *= cq[r];               \
        }                                                                     \
        float tsum = 0.f;                                                     \
        _Pragma("unroll")                                                     \
        for (int n = 0; n < 4; ++n) {                                         \
            float p0 = __builtin_amdgcn_exp2f(s[n][0] - mr);                  \
            float p1 = __builtin_amdgcn_exp2f(s[n][1] - mr);                  \
            float p2 = __builtin_amdgcn_exp2f(s[n][2] - mr);                  \
            float p3 = __builtin_amdgcn_exp2f(s[n][3] - mr);                  \
            tsum += (p0 + p1) + (p2 + p3);                                    \
            pk[n][0] = pk2(p0, p1);                                           \
            pk[n][1] = pk2(p2, p3);                                           \
        }                                                                     \
        tsum += __shfl_xor(tsum, 16);                                         \
        tsum += __shfl_xor(tsum, 32);                                         \
        lr += tsum;                                                           \
    } while (0)

// rebuild PV A-fragment for one h from packed P (permlane32_swap + swz16)
#define REBUILD_PA(pk, ks, pa)                                                \
    do {                                                                      \
        auto sw0 = __builtin_amdgcn_permlane32_swap(pk[2 * ks][0], pk[2 * ks + 1][0], false, false); \
        auto sw1 = __builtin_amdgcn_permlane32_swap(pk[2 * ks][1], pk[2 * ks + 1][1], false, false); \
        unsigned int S0x = sw0[0], S0y = sw0[1];                              \
        unsigned int S1x = sw1[0], S1y = sw1[1];                              \
        unsigned int T0 = (unsigned int)__builtin_amdgcn_ds_swizzle((int)S0y, 0x401F); \
        unsigned int U0 = (unsigned int)__builtin_amdgcn_ds_swizzle((int)S0x, 0x401F); \
        unsigned int T1 = (unsigned int)__builtin_amdgcn_ds_swizzle((int)S1y, 0x401F); \
        unsigned int U1 = (unsigned int)__builtin_amdgcn_ds_swizzle((int)S1x, 0x401F); \
        pa.u[0] = odd ? T0 : S0x;                                             \
        pa.u[1] = odd ? T1 : S1x;                                             \
        pa.u[2] = odd ? S0y : U0;                                             \
        pa.u[3] = odd ? S1y : U1;                                             \
    } while (0)

    for (int t = 0; t < NT; ++t) {
        __syncthreads();                 // all waves done reading tile t-1
        write_tile_lds();
        __syncthreads();                 // tile t visible
        if (t + 1 < NT) load_tile_regs(t + 1);   // latency hidden under compute(t)

        // ---- QK^T (swapped), BOTH h over shared kb reads; mask in C-init ----
        f32x4 s40[4], s41[4];
        __builtin_amdgcn_s_setprio(1);
#pragma unroll
        for (int n = 0; n < 4; ++n) {
            f32x4 mm = *(const f32x4*)&Madd[t * KT + 16 * n + 4 * g];
            bf16x8 kb0 = *(const bf16x8*)
                &Klds[(16 * n + l15) * DD + ((8 * g) ^ swq)];
            bf16x8 kb1 = *(const bf16x8*)
                &Klds[(16 * n + l15) * DD + ((32 + 8 * g) ^ swq)];
            f32x4 a0 = __builtin_amdgcn_mfma_f32_16x16x32_bf16(kb0, qa[0][0], mm, 0, 0, 0);
            s40[n]   = __builtin_amdgcn_mfma_f32_16x16x32_bf16(kb1, qa[0][1], a0, 0, 0, 0);
            f32x4 a1 = __builtin_amdgcn_mfma_f32_16x16x32_bf16(kb0, qa[1][0], mm, 0, 0, 0);
            s41[n]   = __builtin_amdgcn_mfma_f32_16x16x32_bf16(kb1, qa[1][1], a1, 0, 0, 0);
        }
        __builtin_amdgcn_s_setprio(0);

        // ---- softmax both halves ----
        unsigned int pk0[4][2], pk1[4][2];
        SOFTMAX_H(s40, m0, l0, Oacc0, pk0);
        SOFTMAX_H(s41, m1, l1, Oacc1, pk1);

        // ---- joint PV: vb read once, feeds both h ----
        __builtin_amdgcn_s_setprio(1);
        const bool odd = (g & 1);
#pragma unroll
        for (int ks = 0; ks < 2; ++ks) {
            union { bf16x8 v; unsigned int u[4]; } pa0, pa1;
            REBUILD_PA(pk0, ks, pa0);
            REBUILD_PA(pk1, ks, pa1);
#pragma unroll
            for (int dt = 0; dt < 4; ++dt) {
                bf16x8 vb = *(const bf16x8*)
                    &Vlds[(dt * 16 + l15) * KT + ((ks * 32 + 8 * g) ^ swq)];
                Oacc0[dt] = __builtin_amdgcn_mfma_f32_16x16x32_bf16(pa0.v, vb, Oacc0[dt], 0, 0, 0);
                Oacc1[dt] = __builtin_amdgcn_mfma_f32_16x16x32_bf16(pa1.v, vb, Oacc1[dt], 0, 0, 0);
            }
        }
        __builtin_amdgcn_s_setprio(0);
    }

    // ---- epilogue: O[q=4g+r][d=16dt+l15] /= l(q), both halves ----
#pragma unroll
    for (int h = 0; h < 2; ++h) {
        float inv = 1.0f / (h ? l1 : l0);
        float invq[4];
#pragma unroll
        for (int r = 0; r < 4; ++r) invq[r] = __shfl(inv, 4 * g + r);
        const size_t rowbase = (size_t)(bh * SS + qt * QB + h * 64 + w * 16);
#pragma unroll
        for (int dt = 0; dt < 4; ++dt)
#pragma unroll
            for (int r = 0; r < 4; ++r)
                Out[(rowbase + 4 * g + r) * DD + dt * 16 + l15] =
                    (h ? Oacc1[dt][r] : Oacc0[dt][r]) * invq[r];
    }
}

extern "C" void kernel_launch(void* const* d_in, const int* in_sizes, int n_in,
                              void* d_out, int out_size, void* d_ws, size_t ws_size,
                              hipStream_t stream) {
    const float* Q   = (const float*)d_in[0];
    const float* K   = (const float*)d_in[1];
    const float* V   = (const float*)d_in[2];
    const int* mask  = (const int*)d_in[5];
    float* out       = (float*)d_out;

    attn_kernel<<<dim3(BH, NQT), 256, 0, stream>>>(Q, K, V, mask, out);
}